// Round 1
// baseline (492.054 us; speedup 1.0000x reference)
//
#include <hip/hip_runtime.h>
#include <hip/hip_bf16.h>
#include <math.h>

// ---------------------------------------------------------------------------
// int8-quantized MLP: y = (gelu(x @ (w1q*s1)^T + b1)) @ (w2q*s2)^T + b2
// Strategy: bf16 MFMA GEMMs (m97 structure: 128x128 tile, BK=64,
// global_load_lds width-16, 2-barrier K-loop), scales applied in epilogue
// (exact), weights int8->bf16 (exact), x fp32->bf16 (only lossy step).
// ---------------------------------------------------------------------------

typedef short bf16x8 __attribute__((ext_vector_type(8)));
typedef float f32x4 __attribute__((ext_vector_type(4)));

__device__ __forceinline__ unsigned short f2bf(float f) {
  unsigned int x = __float_as_uint(f);
  unsigned int r = (x + 0x7FFFu + ((x >> 16) & 1u)) >> 16;  // RNE
  return (unsigned short)r;
}

// ---- conversion kernels ----------------------------------------------------

__global__ void cvt_f32_bf16(const float* __restrict__ in,
                             unsigned short* __restrict__ out, int n4) {
  int i = blockIdx.x * blockDim.x + threadIdx.x;
  if (i >= n4) return;
  float4 v = reinterpret_cast<const float4*>(in)[i];
  ushort4 o;
  o.x = f2bf(v.x); o.y = f2bf(v.y); o.z = f2bf(v.z); o.w = f2bf(v.w);
  reinterpret_cast<ushort4*>(out)[i] = o;
}

__global__ void cvt_i32_bf16(const int* __restrict__ in,
                             unsigned short* __restrict__ out, int n4) {
  int i = blockIdx.x * blockDim.x + threadIdx.x;
  if (i >= n4) return;
  int4 v = reinterpret_cast<const int4*>(in)[i];
  ushort4 o;  // int8-range values are exact in bf16
  o.x = f2bf((float)v.x); o.y = f2bf((float)v.y);
  o.z = f2bf((float)v.z); o.w = f2bf((float)v.w);
  reinterpret_cast<ushort4*>(out)[i] = o;
}

// ---- GEMM: C[M,N] = A[M,K] @ B[N,K]^T, bf16 in, epilogue fused -------------
// EPI=0: h = gelu(acc*s[n]+b[n]) -> bf16     EPI=1: y = acc*s[n]+b[n] -> f32

#define BM 128
#define BN 128
#define BK 64

template <int EPI>
__global__ __launch_bounds__(256, 2) void gemm_bt(
    const unsigned short* __restrict__ A, const unsigned short* __restrict__ Bw,
    const float* __restrict__ scale, const float* __restrict__ bias,
    void* __restrict__ Cout, int M, int N, int K) {
  __shared__ unsigned short As[BM * BK];
  __shared__ unsigned short Bs[BN * BK];

  // bijective XCD swizzle (m204 form; safe for any nwg)
  const int nwg = gridDim.x;
  const int orig = blockIdx.x;
  const int q = nwg >> 3, r = nwg & 7;
  const int xcd = orig & 7, idx = orig >> 3;
  const int swz =
      (xcd < r ? xcd * (q + 1) : r * (q + 1) + (xcd - r) * q) + idx;

  const int nBn = N / BN;
  const int bm = (swz / nBn) * BM;
  const int bn = (swz % nBn) * BN;

  const int tid = threadIdx.x;
  const int lane = tid & 63;
  const int wid = tid >> 6;
  const int wm = (wid >> 1) * 64;  // wave's 64x64 quadrant
  const int wn = (wid & 1) * 64;

  // staging decomposition: 256 thr * 16B = 4KB = 32 rows of 64 bf16
  const int r0 = tid >> 3;            // 0..31
  const int c0 = (tid & 7) * 8;       // element col within BK

  const unsigned short* aSrc = A + (size_t)(bm + r0) * K + c0;
  const unsigned short* bSrc = Bw + (size_t)(bn + r0) * K + c0;
  unsigned short* aDst = &As[r0 * BK + c0];
  unsigned short* bDst = &Bs[r0 * BK + c0];

  f32x4 acc[4][4];
#pragma unroll
  for (int i = 0; i < 4; ++i)
#pragma unroll
    for (int j = 0; j < 4; ++j) acc[i][j] = 0.0f;

  const int kIters = K / BK;
  for (int ks = 0; ks < kIters; ++ks) {
    const unsigned short* aS = aSrc + ks * BK;
    const unsigned short* bS = bSrc + ks * BK;
#pragma unroll
    for (int i = 0; i < 4; ++i) {
      __builtin_amdgcn_global_load_lds(
          (const __attribute__((address_space(1))) void*)(aS + (size_t)i * 32 * K),
          (__attribute__((address_space(3))) void*)(aDst + i * 32 * BK), 16, 0, 0);
    }
#pragma unroll
    for (int i = 0; i < 4; ++i) {
      __builtin_amdgcn_global_load_lds(
          (const __attribute__((address_space(1))) void*)(bS + (size_t)i * 32 * K),
          (__attribute__((address_space(3))) void*)(bDst + i * 32 * BK), 16, 0, 0);
    }
    __syncthreads();  // compiler drains vmcnt before s_barrier

#pragma unroll
    for (int kk = 0; kk < BK; kk += 32) {
      const int kOff = kk + (lane >> 4) * 8;
      bf16x8 a[4], b[4];
#pragma unroll
      for (int mi = 0; mi < 4; ++mi)
        a[mi] = *(const bf16x8*)&As[(wm + mi * 16 + (lane & 15)) * BK + kOff];
#pragma unroll
      for (int ni = 0; ni < 4; ++ni)
        b[ni] = *(const bf16x8*)&Bs[(wn + ni * 16 + (lane & 15)) * BK + kOff];
#pragma unroll
      for (int mi = 0; mi < 4; ++mi)
#pragma unroll
        for (int ni = 0; ni < 4; ++ni)
          acc[mi][ni] = __builtin_amdgcn_mfma_f32_16x16x32_bf16(
              a[mi], b[ni], acc[mi][ni], 0, 0, 0);
    }
    __syncthreads();
  }

  // epilogue: C/D map col = lane&15, row = (lane>>4)*4 + q  [m89/m91 verified]
  const int cr = (lane >> 4) * 4;
  const int cc = lane & 15;
#pragma unroll
  for (int ni = 0; ni < 4; ++ni) {
    const int gn = bn + wn + ni * 16 + cc;
    const float sv = scale[gn];
    const float bv = bias[gn];
#pragma unroll
    for (int mi = 0; mi < 4; ++mi) {
#pragma unroll
      for (int qq = 0; qq < 4; ++qq) {
        const size_t gm = (size_t)(bm + wm + mi * 16 + cr + qq);
        float v = acc[mi][ni][qq] * sv + bv;
        if (EPI == 0) {
          v = 0.5f * v * (1.0f + erff(v * 0.70710678118654752f));  // exact GELU
          ((unsigned short*)Cout)[gm * N + gn] = f2bf(v);
        } else {
          ((float*)Cout)[gm * N + gn] = v;
        }
      }
    }
  }
}

// ---- launch ---------------------------------------------------------------

extern "C" void kernel_launch(void* const* d_in, const int* in_sizes, int n_in,
                              void* d_out, int out_size, void* d_ws,
                              size_t ws_size, hipStream_t stream) {
  const float* x = (const float*)d_in[0];
  const int* w1q = (const int*)d_in[1];
  const float* s1 = (const float*)d_in[2];
  const float* b1 = (const float*)d_in[3];
  const int* w2q = (const int*)d_in[4];
  const float* s2 = (const float*)d_in[5];
  const float* b2 = (const float*)d_in[6];

  const int H = in_sizes[3];             // b1: [H]
  const int D = in_sizes[6];             // b2: [D]
  const int M = in_sizes[0] / D;         // x: [M, D]

  char* ws = (char*)d_ws;
  unsigned short* xb = (unsigned short*)ws;  ws += (size_t)M * D * 2;
  unsigned short* w1b = (unsigned short*)ws; ws += (size_t)H * D * 2;
  unsigned short* w2b = (unsigned short*)ws; ws += (size_t)D * H * 2;
  unsigned short* hb = (unsigned short*)ws;  ws += (size_t)M * H * 2;

  {
    int n4 = M * D / 4;
    cvt_f32_bf16<<<(n4 + 255) / 256, 256, 0, stream>>>(x, xb, n4);
  }
  {
    int n4 = H * D / 4;
    cvt_i32_bf16<<<(n4 + 255) / 256, 256, 0, stream>>>(w1q, w1b, n4);
    cvt_i32_bf16<<<(n4 + 255) / 256, 256, 0, stream>>>(w2q, w2b, n4);
  }

  // GEMM1: [M,D] x [H,D]^T -> h[M,H] (gelu, bf16)
  gemm_bt<0><<<(M / BM) * (H / BN), 256, 0, stream>>>(
      xb, w1b, s1, b1, (void*)hb, M, H, D);
  // GEMM2: [M,H] x [D,H]^T -> y[M,D] (f32)
  gemm_bt<1><<<(M / BM) * (D / BN), 256, 0, stream>>>(
      hb, w2b, s2, b2, d_out, M, D, H);
}

// Round 8
// 462.928 us; speedup vs baseline: 1.0629x; 1.0629x over previous
//
#include <hip/hip_runtime.h>
#include <hip/hip_bf16.h>
#include <math.h>

// ---------------------------------------------------------------------------
// int8-quantized MLP: y = (gelu(x @ (w1q*s1)^T + b1)) @ (w2q*s2)^T + b2
// Round 8: DIAGNOSTIC + upgrade. Rounds 4/7 failed with IDENTICAL error
// (=max|ref|, i.e. d_out never written) using 160KB/128KB static LDS.
// Theory T-A: static __shared__ > 64KB silently fails to launch in this
// harness (launch-config errors don't surface at hipStreamSynchronize).
// This round keeps the ENTIRE 8-phase machinery but fits LDS in 64 KiB:
//   256x256 tile, BK=32, 8 slots x 8KB = 2(parity) x {A0,A1,B0,B1}
//   slot(X_T) = (T&1)*4 + w;  1 global_load_lds per thread per half-tile
//   schedule per tile kt: p0:STG A0(kt+1) p1:A1(kt+1) p2:B0(kt+2)
//                         p3:B1(kt+2)+vmcnt(2)
//   ledger: VM2 @ p3 retires through A1(kt+1) (oldest-first) -> tile kt+1
//   resident at its p0; evictions >= 2 closed barriers after last read.
// Swizzle (T2): col ^= (row&3)<<3 (elements); applied to the global SOURCE
// (linear LDS dest = 16*tid bytes, m104-safe) and to the ds_read address.
// Residual conflict ~4-way (32-col tile can only spread 4 ways) = m201's
// post-swizzle level.
// ---------------------------------------------------------------------------

typedef short bf16x8 __attribute__((ext_vector_type(8)));
typedef float f32x4 __attribute__((ext_vector_type(4)));
typedef unsigned short u16x8 __attribute__((ext_vector_type(8)));

__device__ __forceinline__ unsigned short f2bf(float f) {
  unsigned int x = __float_as_uint(f);
  unsigned int r = (x + 0x7FFFu + ((x >> 16) & 1u)) >> 16;  // RNE
  return (unsigned short)r;
}

// ---- conversion kernels (grid-stride, 16B loads+stores) --------------------

__global__ void cvt_f32_bf16(const float* __restrict__ in,
                             unsigned short* __restrict__ out, int n8) {
  const int stride = gridDim.x * blockDim.x;
  for (int i = blockIdx.x * blockDim.x + threadIdx.x; i < n8; i += stride) {
    const float4* p = (const float4*)(in + (size_t)i * 8);
    float4 v0 = p[0], v1 = p[1];
    u16x8 o;
    o[0] = f2bf(v0.x); o[1] = f2bf(v0.y); o[2] = f2bf(v0.z); o[3] = f2bf(v0.w);
    o[4] = f2bf(v1.x); o[5] = f2bf(v1.y); o[6] = f2bf(v1.z); o[7] = f2bf(v1.w);
    *(u16x8*)(out + (size_t)i * 8) = o;
  }
}

__global__ void cvt_i32_bf16(const int* __restrict__ in,
                             unsigned short* __restrict__ out, int n8) {
  const int stride = gridDim.x * blockDim.x;
  for (int i = blockIdx.x * blockDim.x + threadIdx.x; i < n8; i += stride) {
    const int4* p = (const int4*)(in + (size_t)i * 8);
    int4 v0 = p[0], v1 = p[1];
    u16x8 o;  // int8-range values exact in bf16
    o[0] = f2bf((float)v0.x); o[1] = f2bf((float)v0.y);
    o[2] = f2bf((float)v0.z); o[3] = f2bf((float)v0.w);
    o[4] = f2bf((float)v1.x); o[5] = f2bf((float)v1.y);
    o[6] = f2bf((float)v1.z); o[7] = f2bf((float)v1.w);
    *(u16x8*)(out + (size_t)i * 8) = o;
  }
}

// ---- 256x256 8-phase GEMM, BK=32: C[M,N] = A[M,K] @ B[N,K]^T ---------------

#define NSLOT 8
#define SLOTE 4096  // ushorts per 8KB half-tile slot (128 rows x 32)

// stage half-tile: T = K-tile index (32 wide), w: 0=A0,1=A1,2=B0,3=B1
__device__ __forceinline__ void stage_half(
    const unsigned short* __restrict__ gA, const unsigned short* __restrict__ gB,
    int bm, int bn, int K, unsigned short* lds, int T, int w, int tid) {
  const unsigned short* base =
      (w >= 2) ? (gB + (size_t)(bn + (w & 1) * 128) * K)
               : (gA + (size_t)(bm + (w & 1) * 128) * K);
  base += T * 32;
  unsigned short* slot = lds + ((((T & 1) << 2) | w) * SLOTE);
  const int lr = tid >> 2;                       // 0..127
  const int colD = (tid & 3) * 8;                // linear LDS col (elements)
  const int colS = colD ^ ((lr & 3) << 3);       // pre-swizzled global col
  // LDS dest element offset = lr*32 + colD = 8*tid -> byte 16*tid (m104-safe)
  __builtin_amdgcn_global_load_lds(
      (const __attribute__((address_space(1))) void*)(base + (size_t)lr * K + colS),
      (__attribute__((address_space(3))) void*)(slot + lr * 32 + colD), 16, 0, 0);
}

// row&3 == lane&3 for all DS rows (mi*16, bRow multiples of 4)
#define DS_A(asl, mi) \
  (*(const bf16x8*)&lds[(asl) * SLOTE + ((mi) * 16 + l15) * 32 + c0])
#define DS_B(bsl, ni) \
  (*(const bf16x8*)&lds[(bsl) * SLOTE + (bRow + (ni) * 16 + l15) * 32 + c0])

#define PHASE(p, sAslot, sBslot, STAGE, VM)                                    \
  {                                                                            \
    bf16x8 a0, a1;                                                             \
    if ((p) == 0) {                                                            \
      _Pragma("unroll") for (int ni = 0; ni < 4; ++ni) bfr[ni] =               \
          DS_B(sBslot, ni);                                                    \
    }                                                                          \
    a0 = DS_A(sAslot, 2 * (p));                                                \
    a1 = DS_A(sAslot, 2 * (p) + 1);                                            \
    STAGE;                                                                     \
    VM;                                                                        \
    __builtin_amdgcn_s_barrier();                                              \
    asm volatile("s_waitcnt lgkmcnt(0)" ::: "memory");                         \
    __builtin_amdgcn_sched_barrier(0);                                         \
    __builtin_amdgcn_s_setprio(1);                                             \
    _Pragma("unroll") for (int ni = 0; ni < 4; ++ni) {                         \
      acc[2 * (p)][ni] = __builtin_amdgcn_mfma_f32_16x16x32_bf16(              \
          a0, bfr[ni], acc[2 * (p)][ni], 0, 0, 0);                             \
      acc[2 * (p) + 1][ni] = __builtin_amdgcn_mfma_f32_16x16x32_bf16(          \
          a1, bfr[ni], acc[2 * (p) + 1][ni], 0, 0, 0);                         \
    }                                                                          \
    __builtin_amdgcn_s_setprio(0);                                             \
    __builtin_amdgcn_sched_barrier(0);                                         \
    __builtin_amdgcn_s_barrier();                                              \
  }

#define VM2 asm volatile("s_waitcnt vmcnt(2)" ::: "memory")
#define VM0 asm volatile("s_waitcnt vmcnt(0)" ::: "memory")
#define STG(T_, w_) stage_half(A, Bw, bm, bn, K, lds, (T_), (w_), tid)

template <int EPI>
__global__ __launch_bounds__(512) void gemm8p(
    const unsigned short* __restrict__ A, const unsigned short* __restrict__ Bw,
    const float* __restrict__ scale, const float* __restrict__ bias,
    void* __restrict__ Cout, int M, int N, int K) {
  __shared__ unsigned short lds[NSLOT * SLOTE];  // 64 KiB static

  // bijective XCD swizzle (m204)
  const int nwg = gridDim.x;
  const int orig = blockIdx.x;
  const int qx = nwg >> 3, rx = nwg & 7;
  const int xcd = orig & 7, sidx = orig >> 3;
  const int swz =
      (xcd < rx ? xcd * (qx + 1) : rx * (qx + 1) + (xcd - rx) * qx) + sidx;

  const int nBn = N / 256;
  const int bm = (swz / nBn) * 256;
  const int bn = (swz % nBn) * 256;

  const int tid = threadIdx.x;
  const int lane = tid & 63;
  const int wid = tid >> 6;
  const int wm = wid >> 2;  // 0..1 : A-half / 128-row block
  const int wn = wid & 3;   // 0..3 : 64-col block

  const int l15 = lane & 15;
  const int c0 = (((lane >> 4) * 8)) ^ ((lane & 3) << 3);  // swizzled k-col
  const int bRow = (wn & 1) * 64;
  const int bHalf = 2 + (wn >> 1);  // this wave's B half id

  f32x4 acc[8][4];
#pragma unroll
  for (int i = 0; i < 8; ++i)
#pragma unroll
    for (int j = 0; j < 4; ++j) acc[i][j] = 0.0f;

  bf16x8 bfr[4];  // B frags [ni], live across the 4 phases of a K-tile

  const int KT = K / 32;

  // prologue: B0(0),B1(0),A0(0),A1(0),B0(1),B1(1); VM2 -> tile 0 resident
  STG(0, 2); STG(0, 3); STG(0, 0); STG(0, 1); STG(1, 2); STG(1, 3);
  VM2;
  __builtin_amdgcn_s_barrier();

  for (int kt = 0; kt <= KT - 3; ++kt) {
    const int sA = ((kt & 1) << 2) | wm;
    const int sB = ((kt & 1) << 2) | bHalf;
    PHASE(0, sA, sB, STG(kt + 1, 0), );
    PHASE(1, sA, sB, STG(kt + 1, 1), );
    PHASE(2, sA, sB, STG(kt + 2, 2), );
    PHASE(3, sA, sB, STG(kt + 2, 3), VM2);
  }
  {  // tile KT-2: stage A(KT-1) only; drain at p3
    const int kt = KT - 2;
    const int sA = ((kt & 1) << 2) | wm;
    const int sB = ((kt & 1) << 2) | bHalf;
    PHASE(0, sA, sB, STG(kt + 1, 0), );
    PHASE(1, sA, sB, STG(kt + 1, 1), );
    PHASE(2, sA, sB, , );
    PHASE(3, sA, sB, , VM0);
  }
  {  // tile KT-1: nothing left to stage
    const int kt = KT - 1;
    const int sA = ((kt & 1) << 2) | wm;
    const int sB = ((kt & 1) << 2) | bHalf;
    PHASE(0, sA, sB, , );
    PHASE(1, sA, sB, , );
    PHASE(2, sA, sB, , );
    PHASE(3, sA, sB, , );
  }

  // epilogue: C/D map col = lane&15, row = (lane>>4)*4 + q  [m89/m91]
  const int crow = (lane >> 4) * 4;
#pragma unroll
  for (int ni = 0; ni < 4; ++ni) {
    const int gn = bn + wn * 64 + ni * 16 + l15;
    const float sv = scale[gn];
    const float bv = bias[gn];
#pragma unroll
    for (int mi = 0; mi < 8; ++mi) {
#pragma unroll
      for (int qv = 0; qv < 4; ++qv) {
        const size_t gm = (size_t)(bm + wm * 128 + mi * 16 + crow + qv);
        float v = acc[mi][ni][qv] * sv + bv;
        if (EPI == 0) {
          v = 0.5f * v * (1.0f + erff(v * 0.70710678118654752f));  // exact GELU
          ((unsigned short*)Cout)[gm * N + gn] = f2bf(v);
        } else {
          ((float*)Cout)[gm * N + gn] = v;
        }
      }
    }
  }
}

// ---- launch ---------------------------------------------------------------

extern "C" void kernel_launch(void* const* d_in, const int* in_sizes, int n_in,
                              void* d_out, int out_size, void* d_ws,
                              size_t ws_size, hipStream_t stream) {
  const float* x = (const float*)d_in[0];
  const int* w1q = (const int*)d_in[1];
  const float* s1 = (const float*)d_in[2];
  const float* b1 = (const float*)d_in[3];
  const int* w2q = (const int*)d_in[4];
  const float* s2 = (const float*)d_in[5];
  const float* b2 = (const float*)d_in[6];

  const int H = in_sizes[3];      // b1: [H]
  const int D = in_sizes[6];      // b2: [D]
  const int M = in_sizes[0] / D;  // x: [M, D]

  char* ws = (char*)d_ws;
  unsigned short* xb = (unsigned short*)ws;  ws += (size_t)M * D * 2;
  unsigned short* w1b = (unsigned short*)ws; ws += (size_t)H * D * 2;
  unsigned short* w2b = (unsigned short*)ws; ws += (size_t)D * H * 2;
  unsigned short* hb = (unsigned short*)ws;  ws += (size_t)M * H * 2;

  cvt_f32_bf16<<<2048, 256, 0, stream>>>(x, xb, M * D / 8);
  cvt_i32_bf16<<<2048, 256, 0, stream>>>(w1q, w1b, H * D / 8);
  cvt_i32_bf16<<<2048, 256, 0, stream>>>(w2q, w2b, D * H / 8);

  // GEMM1: [M,D] x [H,D]^T -> h[M,H] (gelu, bf16)
  gemm8p<0><<<(M / 256) * (H / 256), 512, 0, stream>>>(
      xb, w1b, s1, b1, (void*)hb, M, H, D);
  // GEMM2: [M,H] x [D,H]^T -> y[M,D] (f32)
  gemm8p<1><<<(M / 256) * (D / 256), 512, 0, stream>>>(
      hb, w2b, s2, b2, d_out, M, D, H);
}